// Round 6
// baseline (412.869 us; speedup 1.0000x reference)
//
#include <hip/hip_runtime.h>
#include <hip/hip_bf16.h>

// LSTM: B=1024, T=512, I=4, H=128, O=4. Gate order i,f,g,o (PyTorch).
// out = h_T @ W_fc^T + b_fc
//
// 64 blocks x 16 batch rows, full T-loop on-chip. Per step:
// gates(512x16) = W_scaled @ [h]^T via mfma_f32_16x16x32_bf16 (4 K-chunks)
// + x-projection as register-only MFMAs at the END of the step (acc init =
// bias + Wx@x(t+1)), overlapping the tail VALU + barrier wait.
// A = weights (registers, whole kernel), B = h^T from LDS double-buffer.
// D: col(lane&15)=batch row, row(grp*4+r)=gate col -> thread owns 4
// consecutive hidden cols of one batch row for all 4 gates -> in-register
// c/h update, one packed ds_write_b64 for h.
// Weights pre-scaled by log2e (2*log2e for g-gate): sigmoid = rcp(1+exp2(-x)).
//
// ROUND 6: rocprof showed matrix busy (620cyc) + VALU busy (1160cyc) ~= step
// time (1875cyc) -> pipes near-perfectly SERIAL. Force cross-pipe overlap at
// compile time via sched_group_barrier (T19): interleave gate-chain MFMAs
// with the previous chain's activations, 1 MFMA : 3-4 VALU. Arithmetic is
// bit-identical to the passing round-5 kernel.

#define Tlen 512
#define Iin  4
#define Hdim 128
#define Odim 4

// sched_group_barrier masks (LLVM AMDGPU SchedGroupMask)
#define SGB(mask, n) __builtin_amdgcn_sched_group_barrier((mask), (n), 0)
#define M_VALU  0x2
#define M_MFMA  0x8
#define M_VMEMR 0x20
#define M_DSR   0x100

typedef __attribute__((ext_vector_type(8))) short bf16x8;
typedef __attribute__((ext_vector_type(4))) float f32x4;
typedef __attribute__((ext_vector_type(2))) unsigned uint2v;
typedef __attribute__((ext_vector_type(4))) unsigned uint4v;

static __device__ __forceinline__ short f2bf(float f) {
  union { float f; unsigned u; } v; v.f = f;
  unsigned u = v.u;
  return (short)((u + 0x7FFFu + ((u >> 16) & 1u)) >> 16);  // RNE
}
static __device__ __forceinline__ unsigned cvt_pk_bf16(float lo, float hi) {
  unsigned r;
  asm("v_cvt_pk_bf16_f32 %0, %1, %2" : "=v"(r) : "v"(lo), "v"(hi));
  return r;
}
static __device__ __forceinline__ float ex2(float x) { return __builtin_amdgcn_exp2f(x); }
static __device__ __forceinline__ float rcp_(float x) { return __builtin_amdgcn_rcpf(x); }

#define MFMA __builtin_amdgcn_mfma_f32_16x16x32_bf16

__global__ __launch_bounds__(512) void lstm_kernel(
    const float* __restrict__ x, const float* __restrict__ W_ih,
    const float* __restrict__ W_hh, const float* __restrict__ b_ih,
    const float* __restrict__ b_hh, const float* __restrict__ W_fc,
    const float* __restrict__ b_fc, float* __restrict__ out) {
  // h double-buffer: [buf][batch row][k]; row stride 168 shorts = 336 B
  // (b128-aligned; measured-benign banking). Cols 0..127 = h, rest unused/0.
  __shared__ alignas(16) short Albuf[2][16][168];
  __shared__ float hfin[16][Hdim];

  const int tid  = threadIdx.x;
  const int wid  = tid >> 6;    // wave 0..7 -> hidden cols wid*16..+15
  const int lane = tid & 63;
  const int m16  = lane & 15;   // batch row / weight row within tile
  const int grp  = lane >> 4;   // k-group 0..3
  const int bbase = blockIdx.x * 16;
  const float L2E = 1.4426950408889634f;

  // ---- weight fragments (A-operand), pre-scaled, registers for whole kernel ----
  // A-frag lane l elem e = A[m = l&15][k = kc*32 + (l>>4)*8 + e]
  bf16x8 Wf[4][4];
  bf16x8 Wx[4];
  f32x4  c0v[4];
#pragma unroll
  for (int q = 0; q < 4; ++q) {
    const float sc = (q == 2) ? 2.0f * L2E : L2E;   // g-gate: tanh needs 2x
    const int gm = q * 128 + wid * 16 + m16;        // weight row this lane holds
#pragma unroll
    for (int kc = 0; kc < 4; ++kc) {
      const float* src = W_hh + (size_t)gm * Hdim + kc * 32 + grp * 8;
      bf16x8 w;
#pragma unroll
      for (int e = 0; e < 8; ++e) w[e] = f2bf(src[e] * sc);
      Wf[q][kc] = w;
    }
    bf16x8 w4 = {0, 0, 0, 0, 0, 0, 0, 0};  // x-chunk A: [W_ih(4)|0...] at k=0..3
    if (grp == 0) {
#pragma unroll
      for (int e = 0; e < 4; ++e) w4[e] = f2bf(W_ih[gm * Iin + e] * sc);
    }
    Wx[q] = w4;
#pragma unroll
    for (int r = 0; r < 4; ++r) {
      const int gr = q * 128 + wid * 16 + grp * 4 + r;  // this thread's gate col
      c0v[q][r] = (b_ih[gr] + b_hh[gr]) * sc;
    }
  }

  // ---- zero h buffers ----
  for (int i = tid; i < 2 * 16 * 168; i += 512) ((short*)Albuf)[i] = 0;

  const float* xrow = x + (size_t)(bbase + m16) * (Tlen * Iin);

  // ---- acc = bias + Wx @ x(0) (register-only MFMAs, no LDS dependency) ----
  // B garbage at k>=4 (and k>=8 for grp!=0 lanes) multiplies A==0 exactly; x is
  // finite so 0*finite == 0 -> no lane guards needed.
  f32x4 acc0, acc1, acc2, acc3;
  {
    f32x4 xv = *(const f32x4*)xrow;
    uint4v u;
    u[0] = cvt_pk_bf16(xv[0], xv[1]);
    u[1] = cvt_pk_bf16(xv[2], xv[3]);
    u[2] = 0; u[3] = 0;
    union { uint4v uu; bf16x8 v; } cst; cst.uu = u;
    acc0 = MFMA(Wx[0], cst.v, c0v[0], 0, 0, 0);
    acc1 = MFMA(Wx[1], cst.v, c0v[1], 0, 0, 0);
    acc2 = MFMA(Wx[2], cst.v, c0v[2], 0, 0, 0);
    acc3 = MFMA(Wx[3], cst.v, c0v[3], 0, 0, 0);
  }

  float c4[4] = {0.f, 0.f, 0.f, 0.f};
  float hl[4] = {0.f, 0.f, 0.f, 0.f};
  __syncthreads();

#pragma unroll 2
  for (int t = 0; t < Tlen; ++t) {
    const int cur = t & 1, nxt = cur ^ 1;

    // B fragments of h(t)
    bf16x8 b0 = *(const bf16x8*)&Albuf[cur][m16][ 0 + grp * 8];
    bf16x8 b1 = *(const bf16x8*)&Albuf[cur][m16][32 + grp * 8];
    bf16x8 b2 = *(const bf16x8*)&Albuf[cur][m16][64 + grp * 8];
    bf16x8 b3 = *(const bf16x8*)&Albuf[cur][m16][96 + grp * 8];

    // x(t+1) prefetch (clamped dup-load on final step)
    const int tn = (t + 1 < Tlen) ? (t + 1) : (Tlen - 1);
    f32x4 xv = *(const f32x4*)(xrow + (size_t)tn * Iin);

    // ---- gate chains (i,f,g,o); activations feed from completed chains ----
    acc0 = MFMA(Wf[0][0], b0, acc0, 0, 0, 0);
    acc0 = MFMA(Wf[0][1], b1, acc0, 0, 0, 0);
    acc0 = MFMA(Wf[0][2], b2, acc0, 0, 0, 0);
    acc0 = MFMA(Wf[0][3], b3, acc0, 0, 0, 0);

    acc1 = MFMA(Wf[1][0], b0, acc1, 0, 0, 0);
    acc1 = MFMA(Wf[1][1], b1, acc1, 0, 0, 0);
    acc1 = MFMA(Wf[1][2], b2, acc1, 0, 0, 0);
    acc1 = MFMA(Wf[1][3], b3, acc1, 0, 0, 0);
    f32x4 si;
#pragma unroll
    for (int r = 0; r < 4; ++r) si[r] = rcp_(1.0f + ex2(-acc0[r]));

    acc2 = MFMA(Wf[2][0], b0, acc2, 0, 0, 0);
    acc2 = MFMA(Wf[2][1], b1, acc2, 0, 0, 0);
    acc2 = MFMA(Wf[2][2], b2, acc2, 0, 0, 0);
    acc2 = MFMA(Wf[2][3], b3, acc2, 0, 0, 0);
    f32x4 sf;
#pragma unroll
    for (int r = 0; r < 4; ++r) sf[r] = rcp_(1.0f + ex2(-acc1[r]));

    acc3 = MFMA(Wf[3][0], b0, acc3, 0, 0, 0);
    acc3 = MFMA(Wf[3][1], b1, acc3, 0, 0, 0);
    acc3 = MFMA(Wf[3][2], b2, acc3, 0, 0, 0);
    acc3 = MFMA(Wf[3][3], b3, acc3, 0, 0, 0);
    f32x4 gt;
#pragma unroll
    for (int r = 0; r < 4; ++r)
      gt[r] = __builtin_fmaf(2.0f, rcp_(1.0f + ex2(-acc2[r])), -1.0f);

    f32x4 so;
#pragma unroll
    for (int r = 0; r < 4; ++r) so[r] = rcp_(1.0f + ex2(-acc3[r]));

    // cell + hidden update (fp32, in registers)
#pragma unroll
    for (int r = 0; r < 4; ++r) {
      float c = __builtin_fmaf(sf[r], c4[r], si[r] * gt[r]);
      c4[r] = c;
      float tc = __builtin_fmaf(
          2.0f, rcp_(1.0f + ex2(-2.8853900817779268f * c)), -1.0f);
      hl[r] = so[r] * tc;
    }

    // pack h(t+1): 4 consecutive hidden cols -> one ds_write_b64
    uint2v hp;
    hp[0] = cvt_pk_bf16(hl[0], hl[1]);
    hp[1] = cvt_pk_bf16(hl[2], hl[3]);
    *(uint2v*)&Albuf[nxt][m16][wid * 16 + grp * 4] = hp;

    // re-init acc = bias + Wx @ x(t+1) (register-only; overlaps tail/barrier)
    {
      uint4v u;
      u[0] = cvt_pk_bf16(xv[0], xv[1]);
      u[1] = cvt_pk_bf16(xv[2], xv[3]);
      u[2] = 0; u[3] = 0;
      union { uint4v uu; bf16x8 v; } cst; cst.uu = u;
      acc0 = MFMA(Wx[0], cst.v, c0v[0], 0, 0, 0);
      acc1 = MFMA(Wx[1], cst.v, c0v[1], 0, 0, 0);
      acc2 = MFMA(Wx[2], cst.v, c0v[2], 0, 0, 0);
      acc3 = MFMA(Wx[3], cst.v, c0v[3], 0, 0, 0);
    }

    // ---- desired schedule for this iteration (T19) ----
    // head: 4 ds_read, x-load, q0 chain back-to-back
    SGB(M_DSR, 4); SGB(M_VMEMR, 1); SGB(M_MFMA, 4);
    // q1 chain interleaved with sigma_i (exp2,add,rcp per elem = 3 VALU-class)
    SGB(M_MFMA, 1); SGB(M_VALU, 3);
    SGB(M_MFMA, 1); SGB(M_VALU, 3);
    SGB(M_MFMA, 1); SGB(M_VALU, 3);
    SGB(M_MFMA, 1); SGB(M_VALU, 3);
    // q2 chain interleaved with sigma_f
    SGB(M_MFMA, 1); SGB(M_VALU, 3);
    SGB(M_MFMA, 1); SGB(M_VALU, 3);
    SGB(M_MFMA, 1); SGB(M_VALU, 3);
    SGB(M_MFMA, 1); SGB(M_VALU, 3);
    // q3 chain interleaved with tanh_g (exp2,add,rcp,fma = 4 VALU-class)
    SGB(M_MFMA, 1); SGB(M_VALU, 4);
    SGB(M_MFMA, 1); SGB(M_VALU, 4);
    SGB(M_MFMA, 1); SGB(M_VALU, 4);
    SGB(M_MFMA, 1); SGB(M_VALU, 4);
    // x-MFMAs overlap the tail VALU (sigma_o, cell, packs)
    SGB(M_MFMA, 4);

    __syncthreads();
  }

  // ---- final FC: out = h_T @ W_fc^T + b_fc ----
  {
    f32x4 hv;
    hv[0] = hl[0]; hv[1] = hl[1]; hv[2] = hl[2]; hv[3] = hl[3];
    *(f32x4*)&hfin[m16][wid * 16 + grp * 4] = hv;
  }
  __syncthreads();
  if (tid < 64) {
    const int row = tid >> 2, o = tid & 3;
    float s = b_fc[o];
#pragma unroll 8
    for (int k = 0; k < Hdim; ++k) s += hfin[row][k] * W_fc[o * Hdim + k];
    out[(size_t)(bbase + row) * Odim + o] = s;
  }
}

extern "C" void kernel_launch(void* const* d_in, const int* in_sizes, int n_in,
                              void* d_out, int out_size, void* d_ws, size_t ws_size,
                              hipStream_t stream) {
  const float* x    = (const float*)d_in[0];
  const float* W_ih = (const float*)d_in[1];
  const float* W_hh = (const float*)d_in[2];
  const float* b_ih = (const float*)d_in[3];
  const float* b_hh = (const float*)d_in[4];
  const float* W_fc = (const float*)d_in[5];
  const float* b_fc = (const float*)d_in[6];
  float* out = (float*)d_out;
  lstm_kernel<<<64, 512, 0, stream>>>(x, W_ih, W_hh, b_ih, b_hh, W_fc, b_fc, out);
}

// Round 7
// 384.903 us; speedup vs baseline: 1.0727x; 1.0727x over previous
//
#include <hip/hip_runtime.h>
#include <hip/hip_bf16.h>

// LSTM: B=1024, T=512, I=4, H=128, O=4. Gate order i,f,g,o (PyTorch).
// out = h_T @ W_fc^T + b_fc
//
// 64 blocks x 16 batch rows, full T-loop on-chip. Per step:
// gates(512x16) = W_scaled @ [h]^T via mfma_f32_16x16x32_bf16 (4 K-chunks)
// + x-projection as register-only MFMAs at the END of the step (acc init =
// bias + Wx@x(t+1)), draining during the barrier wait.
// A = weights (registers, whole kernel), B = h^T from LDS double-buffer.
// D: col(lane&15)=batch row, row(grp*4+r)=gate col -> thread owns 4
// consecutive hidden cols of one batch row for all 4 gates -> in-register
// c/h update, one packed ds_write_b64 for h.
// Weights pre-scaled by log2e (2*log2e for g-gate): sigmoid = rcp(1+exp2(-x)).
//
// ROUND 7: round-6 PMC showed 15.5 cyc/MFMA (vs 4.85 throughput) -> the
// chain-major MFMA order was DEPENDENCY-serialized (4 serial MFMAs per acc,
// ~17cyc latency each), and VALU waits behind it: 620+1160 ~= 1875 cyc/step.
// Fix: K-MAJOR issue order (k0 of all 4 chains, then k1, ...) -> matrix
// section is throughput-bound (~95 cyc), activations start as soon as acc0
// retires. No SGB (regressed in r6), no unroll pragma, bit-identical math.

#define Tlen 512
#define Iin  4
#define Hdim 128
#define Odim 4

typedef __attribute__((ext_vector_type(8))) short bf16x8;
typedef __attribute__((ext_vector_type(4))) float f32x4;
typedef __attribute__((ext_vector_type(2))) unsigned uint2v;
typedef __attribute__((ext_vector_type(4))) unsigned uint4v;

static __device__ __forceinline__ short f2bf(float f) {
  union { float f; unsigned u; } v; v.f = f;
  unsigned u = v.u;
  return (short)((u + 0x7FFFu + ((u >> 16) & 1u)) >> 16);  // RNE
}
static __device__ __forceinline__ unsigned cvt_pk_bf16(float lo, float hi) {
  unsigned r;
  asm("v_cvt_pk_bf16_f32 %0, %1, %2" : "=v"(r) : "v"(lo), "v"(hi));
  return r;
}
static __device__ __forceinline__ float ex2(float x) { return __builtin_amdgcn_exp2f(x); }
static __device__ __forceinline__ float rcp_(float x) { return __builtin_amdgcn_rcpf(x); }

#define MFMA __builtin_amdgcn_mfma_f32_16x16x32_bf16

__global__ __launch_bounds__(512) void lstm_kernel(
    const float* __restrict__ x, const float* __restrict__ W_ih,
    const float* __restrict__ W_hh, const float* __restrict__ b_ih,
    const float* __restrict__ b_hh, const float* __restrict__ W_fc,
    const float* __restrict__ b_fc, float* __restrict__ out) {
  // h double-buffer: [buf][batch row][k]; row stride 168 shorts = 336 B
  // (b128-aligned; measured-benign banking). Cols 0..127 = h, rest unused/0.
  __shared__ alignas(16) short Albuf[2][16][168];
  __shared__ float hfin[16][Hdim];

  const int tid  = threadIdx.x;
  const int wid  = tid >> 6;    // wave 0..7 -> hidden cols wid*16..+15
  const int lane = tid & 63;
  const int m16  = lane & 15;   // batch row / weight row within tile
  const int grp  = lane >> 4;   // k-group 0..3
  const int bbase = blockIdx.x * 16;
  const float L2E = 1.4426950408889634f;

  // ---- weight fragments (A-operand), pre-scaled, registers for whole kernel ----
  // A-frag lane l elem e = A[m = l&15][k = kc*32 + (l>>4)*8 + e]
  bf16x8 Wf[4][4];
  bf16x8 Wx[4];
  f32x4  c0v[4];
#pragma unroll
  for (int q = 0; q < 4; ++q) {
    const float sc = (q == 2) ? 2.0f * L2E : L2E;   // g-gate: tanh needs 2x
    const int gm = q * 128 + wid * 16 + m16;        // weight row this lane holds
#pragma unroll
    for (int kc = 0; kc < 4; ++kc) {
      const float* src = W_hh + (size_t)gm * Hdim + kc * 32 + grp * 8;
      bf16x8 w;
#pragma unroll
      for (int e = 0; e < 8; ++e) w[e] = f2bf(src[e] * sc);
      Wf[q][kc] = w;
    }
    bf16x8 w4 = {0, 0, 0, 0, 0, 0, 0, 0};  // x-chunk A: [W_ih(4)|0...] at k=0..3
    if (grp == 0) {
#pragma unroll
      for (int e = 0; e < 4; ++e) w4[e] = f2bf(W_ih[gm * Iin + e] * sc);
    }
    Wx[q] = w4;
#pragma unroll
    for (int r = 0; r < 4; ++r) {
      const int gr = q * 128 + wid * 16 + grp * 4 + r;  // this thread's gate col
      c0v[q][r] = (b_ih[gr] + b_hh[gr]) * sc;
    }
  }

  // ---- zero h buffers ----
  for (int i = tid; i < 2 * 16 * 168; i += 512) ((short*)Albuf)[i] = 0;

  const float* xrow = x + (size_t)(bbase + m16) * (Tlen * Iin);

  // ---- acc = bias + Wx @ x(0) (register-only MFMAs, no LDS dependency) ----
  // B garbage at k>=4 multiplies A==0 exactly; x finite -> 0*finite == 0.
  f32x4 acc0, acc1, acc2, acc3;
  {
    f32x4 xv = *(const f32x4*)xrow;
    uint4v u;
    u[0] = cvt_pk_bf16(xv[0], xv[1]);
    u[1] = cvt_pk_bf16(xv[2], xv[3]);
    u[2] = 0; u[3] = 0;
    union { uint4v uu; bf16x8 v; } cst; cst.uu = u;
    acc0 = MFMA(Wx[0], cst.v, c0v[0], 0, 0, 0);
    acc1 = MFMA(Wx[1], cst.v, c0v[1], 0, 0, 0);
    acc2 = MFMA(Wx[2], cst.v, c0v[2], 0, 0, 0);
    acc3 = MFMA(Wx[3], cst.v, c0v[3], 0, 0, 0);
  }

  float c4[4] = {0.f, 0.f, 0.f, 0.f};
  float hl[4] = {0.f, 0.f, 0.f, 0.f};
  __syncthreads();

  for (int t = 0; t < Tlen; ++t) {
    const int cur = t & 1, nxt = cur ^ 1;

    // B fragments of h(t)
    bf16x8 b0 = *(const bf16x8*)&Albuf[cur][m16][ 0 + grp * 8];
    bf16x8 b1 = *(const bf16x8*)&Albuf[cur][m16][32 + grp * 8];
    bf16x8 b2 = *(const bf16x8*)&Albuf[cur][m16][64 + grp * 8];
    bf16x8 b3 = *(const bf16x8*)&Albuf[cur][m16][96 + grp * 8];

    // x(t+1) prefetch (clamped dup-load on final step)
    const int tn = (t + 1 < Tlen) ? (t + 1) : (Tlen - 1);
    f32x4 xv = *(const f32x4*)(xrow + (size_t)tn * Iin);

    // ---- K-MAJOR MFMA issue: k0 of all 4 chains, k1, k2, k3 ----
    // 16 back-to-back independent-chain MFMAs: throughput-bound (~95 cyc),
    // not latency-serialized (r6 measured 15.5 cyc/MFMA with chain-major).
    acc0 = MFMA(Wf[0][0], b0, acc0, 0, 0, 0);
    acc1 = MFMA(Wf[1][0], b0, acc1, 0, 0, 0);
    acc2 = MFMA(Wf[2][0], b0, acc2, 0, 0, 0);
    acc3 = MFMA(Wf[3][0], b0, acc3, 0, 0, 0);

    acc0 = MFMA(Wf[0][1], b1, acc0, 0, 0, 0);
    acc1 = MFMA(Wf[1][1], b1, acc1, 0, 0, 0);
    acc2 = MFMA(Wf[2][1], b1, acc2, 0, 0, 0);
    acc3 = MFMA(Wf[3][1], b1, acc3, 0, 0, 0);

    acc0 = MFMA(Wf[0][2], b2, acc0, 0, 0, 0);
    acc1 = MFMA(Wf[1][2], b2, acc1, 0, 0, 0);
    acc2 = MFMA(Wf[2][2], b2, acc2, 0, 0, 0);
    acc3 = MFMA(Wf[3][2], b2, acc3, 0, 0, 0);

    acc0 = MFMA(Wf[0][3], b3, acc0, 0, 0, 0);
    acc1 = MFMA(Wf[1][3], b3, acc1, 0, 0, 0);
    acc2 = MFMA(Wf[2][3], b3, acc2, 0, 0, 0);
    acc3 = MFMA(Wf[3][3], b3, acc3, 0, 0, 0);

    // ---- activations: each starts as its chain retires (q3 still in flight
    // when sigma_i begins) ----
    f32x4 si;
#pragma unroll
    for (int r = 0; r < 4; ++r) si[r] = rcp_(1.0f + ex2(-acc0[r]));
    f32x4 sf;
#pragma unroll
    for (int r = 0; r < 4; ++r) sf[r] = rcp_(1.0f + ex2(-acc1[r]));
    f32x4 gt;
#pragma unroll
    for (int r = 0; r < 4; ++r)
      gt[r] = __builtin_fmaf(2.0f, rcp_(1.0f + ex2(-acc2[r])), -1.0f);
    f32x4 so;
#pragma unroll
    for (int r = 0; r < 4; ++r) so[r] = rcp_(1.0f + ex2(-acc3[r]));

    // cell + hidden update (fp32, in registers)
#pragma unroll
    for (int r = 0; r < 4; ++r) {
      float c = __builtin_fmaf(sf[r], c4[r], si[r] * gt[r]);
      c4[r] = c;
      float tc = __builtin_fmaf(
          2.0f, rcp_(1.0f + ex2(-2.8853900817779268f * c)), -1.0f);
      hl[r] = so[r] * tc;
    }

    // pack h(t+1): 4 consecutive hidden cols -> one ds_write_b64
    uint2v hp;
    hp[0] = cvt_pk_bf16(hl[0], hl[1]);
    hp[1] = cvt_pk_bf16(hl[2], hl[3]);
    *(uint2v*)&Albuf[nxt][m16][wid * 16 + grp * 4] = hp;

    // re-init acc = bias + Wx @ x(t+1) (register-only; drains during barrier)
    {
      uint4v u;
      u[0] = cvt_pk_bf16(xv[0], xv[1]);
      u[1] = cvt_pk_bf16(xv[2], xv[3]);
      u[2] = 0; u[3] = 0;
      union { uint4v uu; bf16x8 v; } cst; cst.uu = u;
      acc0 = MFMA(Wx[0], cst.v, c0v[0], 0, 0, 0);
      acc1 = MFMA(Wx[1], cst.v, c0v[1], 0, 0, 0);
      acc2 = MFMA(Wx[2], cst.v, c0v[2], 0, 0, 0);
      acc3 = MFMA(Wx[3], cst.v, c0v[3], 0, 0, 0);
    }

    __syncthreads();
  }

  // ---- final FC: out = h_T @ W_fc^T + b_fc ----
  {
    f32x4 hv;
    hv[0] = hl[0]; hv[1] = hl[1]; hv[2] = hl[2]; hv[3] = hl[3];
    *(f32x4*)&hfin[m16][wid * 16 + grp * 4] = hv;
  }
  __syncthreads();
  if (tid < 64) {
    const int row = tid >> 2, o = tid & 3;
    float s = b_fc[o];
#pragma unroll 8
    for (int k = 0; k < Hdim; ++k) s += hfin[row][k] * W_fc[o * Hdim + k];
    out[(size_t)(bbase + row) * Odim + o] = s;
  }
}

extern "C" void kernel_launch(void* const* d_in, const int* in_sizes, int n_in,
                              void* d_out, int out_size, void* d_ws, size_t ws_size,
                              hipStream_t stream) {
  const float* x    = (const float*)d_in[0];
  const float* W_ih = (const float*)d_in[1];
  const float* W_hh = (const float*)d_in[2];
  const float* b_ih = (const float*)d_in[3];
  const float* b_hh = (const float*)d_in[4];
  const float* W_fc = (const float*)d_in[5];
  const float* b_fc = (const float*)d_in[6];
  float* out = (float*)d_out;
  lstm_kernel<<<64, 512, 0, stream>>>(x, W_ih, W_hh, b_ih, b_hh, W_fc, b_fc, out);
}